// Round 1
// baseline (9512.785 us; speedup 1.0000x reference)
//
#include <hip/hip_runtime.h>
#include <math.h>

#define N_V 3072
#define D_E 512
constexpr float LRELU_ALPHA = 0.2f;
constexpr float NEG_INF_F = -9e15f;

// ---------------------------------------------------------------------------
// Tiled fp32 GEMM: C[M,N] = A[M,K] @ B[K,N]
// EPI 0: plain store; EPI 1: ELU; EPI 2: relu(acc + addv[row,col] + bias[col])
// All dims assumed multiples of tile sizes (true here: 3072/512/1024).
// ---------------------------------------------------------------------------
template<int EPI>
__global__ __launch_bounds__(256) void gemm_f32(
    const float* __restrict__ A, int lda,
    const float* __restrict__ B, int ldb,
    float* __restrict__ C, int ldc,
    int M, int N, int K,
    const float* __restrict__ addv, int ldadd,
    const float* __restrict__ bias)
{
    constexpr int BM = 64, BN = 64, BK = 16;
    __shared__ float As[BK][BM + 1];
    __shared__ float Bs[BK][BN + 1];
    const int tid = threadIdx.x;
    const int tx = tid & 15, ty = tid >> 4;
    const int bm = blockIdx.y * BM, bn = blockIdx.x * BN;

    float acc[4][4] = {};

    for (int k0 = 0; k0 < K; k0 += BK) {
        #pragma unroll
        for (int l = 0; l < 4; ++l) {
            int idx = tid + l * 256;
            int m = idx >> 4;     // 0..63
            int k = idx & 15;     // 0..15
            As[k][m] = A[(size_t)(bm + m) * lda + k0 + k];
        }
        #pragma unroll
        for (int l = 0; l < 4; ++l) {
            int idx = tid + l * 256;
            int k = idx >> 6;     // 0..15
            int n = idx & 63;     // 0..63
            Bs[k][n] = B[(size_t)(k0 + k) * ldb + bn + n];
        }
        __syncthreads();
        #pragma unroll
        for (int k = 0; k < BK; ++k) {
            float a[4], b[4];
            #pragma unroll
            for (int i = 0; i < 4; ++i) a[i] = As[k][ty * 4 + i];
            #pragma unroll
            for (int j = 0; j < 4; ++j) b[j] = Bs[k][tx * 4 + j];
            #pragma unroll
            for (int i = 0; i < 4; ++i)
                #pragma unroll
                for (int j = 0; j < 4; ++j)
                    acc[i][j] = fmaf(a[i], b[j], acc[i][j]);
        }
        __syncthreads();
    }

    #pragma unroll
    for (int i = 0; i < 4; ++i) {
        int row = bm + ty * 4 + i;
        #pragma unroll
        for (int j = 0; j < 4; ++j) {
            int col = bn + tx * 4 + j;
            float v = acc[i][j];
            if (EPI == 1) {
                v = v > 0.f ? v : (expf(v) - 1.f);        // ELU, alpha=1
            } else if (EPI == 2) {
                v += addv[(size_t)row * ldadd + col] + bias[col];
                v = v > 0.f ? v : 0.f;                    // ReLU
            }
            C[(size_t)row * ldc + col] = v;
        }
    }
}

// ---------------------------------------------------------------------------
// s[i] = Wh[i,:]·a_src ; d[i] = Wh[i,:]·a_dst   (one wave per row)
// ---------------------------------------------------------------------------
__global__ __launch_bounds__(256) void rowdot2(
    const float* __restrict__ Wh,
    const float* __restrict__ a_src, const float* __restrict__ a_dst,
    float* __restrict__ s, float* __restrict__ d)
{
    const int wave = threadIdx.x >> 6;
    const int lane = threadIdx.x & 63;
    const int row  = blockIdx.x * 4 + wave;
    const float* w = Wh + (size_t)row * D_E;
    float ss = 0.f, dd = 0.f;
    #pragma unroll
    for (int k = 0; k < 8; ++k) {
        int c = lane + k * 64;
        float x = w[c];
        ss = fmaf(x, a_src[c], ss);
        dd = fmaf(x, a_dst[c], dd);
    }
    #pragma unroll
    for (int off = 32; off; off >>= 1) {
        ss += __shfl_down(ss, off);
        dd += __shfl_down(dd, off);
    }
    if (lane == 0) { s[row] = ss; d[row] = dd; }
}

// sq[i] = sum(emb[i,:]^2)
__global__ __launch_bounds__(256) void rowsumsq(
    const float* __restrict__ emb, float* __restrict__ sq)
{
    const int wave = threadIdx.x >> 6;
    const int lane = threadIdx.x & 63;
    const int row  = blockIdx.x * 4 + wave;
    const float* w = emb + (size_t)row * D_E;
    float ss = 0.f;
    #pragma unroll
    for (int k = 0; k < 8; ++k) {
        float x = w[lane + k * 64];
        ss = fmaf(x, x, ss);
    }
    #pragma unroll
    for (int off = 32; off; off >>= 1) ss += __shfl_down(ss, off);
    if (lane == 0) sq[row] = ss;
}

// ---------------------------------------------------------------------------
// Row softmax of masked leaky_relu(s_i + d_j).  MASKMODE 0: adj>0 (neighbors);
// MASKMODE 1: adj==0 && j!=i (non-neighbors).  One block (256 thr) per row.
// ---------------------------------------------------------------------------
template<int MASKMODE>
__global__ __launch_bounds__(256) void att_softmax(
    const float* __restrict__ adj, const float* __restrict__ s,
    const float* __restrict__ dvec, float* __restrict__ att)
{
    const int i = blockIdx.x;
    const int t = threadIdx.x;
    const float si = s[i];
    float e[12];
    float mloc = -3.4e38f;
    #pragma unroll
    for (int l = 0; l < 12; ++l) {
        int j = t + l * 256;
        float a = adj[(size_t)i * N_V + j];
        bool keep = (MASKMODE == 0) ? (a > 0.f) : (a == 0.f && j != i);
        float x = si + dvec[j];
        x = x > 0.f ? x : LRELU_ALPHA * x;
        e[l] = keep ? x : NEG_INF_F;
        mloc = fmaxf(mloc, e[l]);
    }
    __shared__ float red[256];
    red[t] = mloc; __syncthreads();
    for (int o = 128; o; o >>= 1) {
        if (t < o) red[t] = fmaxf(red[t], red[t + o]);
        __syncthreads();
    }
    float m = red[0]; __syncthreads();
    float zloc = 0.f;
    #pragma unroll
    for (int l = 0; l < 12; ++l) { e[l] = expf(e[l] - m); zloc += e[l]; }
    red[t] = zloc; __syncthreads();
    for (int o = 128; o; o >>= 1) {
        if (t < o) red[t] += red[t + o];
        __syncthreads();
    }
    const float zinv = 1.f / red[0];
    #pragma unroll
    for (int l = 0; l < 12; ++l) {
        int j = t + l * 256;
        att[(size_t)i * N_V + j] = e[l] * zinv;
    }
}

// ---------------------------------------------------------------------------
// Glimpse confidence: conf_i = max_j softmax(masked e)_ij = 1/Z_i.
// Accumulates sum_i log(conf_i + 1e-8) into accum (atomic).
// ---------------------------------------------------------------------------
__global__ __launch_bounds__(256) void conf_kernel(
    const float* __restrict__ adj, const float* __restrict__ s,
    const float* __restrict__ dvec, float* __restrict__ accum)
{
    const int i = blockIdx.x;
    const int t = threadIdx.x;
    const float si = s[i];
    float e[12];
    float mloc = -3.4e38f;
    #pragma unroll
    for (int l = 0; l < 12; ++l) {
        int j = t + l * 256;
        float a = adj[(size_t)i * N_V + j];
        float x = si + dvec[j];
        x = x > 0.f ? x : LRELU_ALPHA * x;
        e[l] = (a > 0.f) ? x : NEG_INF_F;
        mloc = fmaxf(mloc, e[l]);
    }
    __shared__ float red[256];
    red[t] = mloc; __syncthreads();
    for (int o = 128; o; o >>= 1) {
        if (t < o) red[t] = fmaxf(red[t], red[t + o]);
        __syncthreads();
    }
    float m = red[0]; __syncthreads();
    float zloc = 0.f;
    #pragma unroll
    for (int l = 0; l < 12; ++l) zloc += expf(e[l] - m);
    red[t] = zloc; __syncthreads();
    for (int o = 128; o; o >>= 1) {
        if (t < o) red[t] += red[t + o];
        __syncthreads();
    }
    if (t == 0) {
        float conf = 1.f / red[0];
        atomicAdd(accum, logf(conf + 1e-8f));
    }
}

// ---------------------------------------------------------------------------
// Edge-only embedding loss: accum -= sum over (i,j): adj_ij>0 of
// sqrt(max(sq_i + sq_j - 2*emb_i·emb_j, 1e-12)).  One block per row.
// ---------------------------------------------------------------------------
__global__ __launch_bounds__(256) void edge_loss(
    const float* __restrict__ adj, const float* __restrict__ emb,
    const float* __restrict__ sq, float* __restrict__ accum)
{
    __shared__ int list[1024];
    __shared__ int cnt;
    __shared__ float wsum[4];
    const int i = blockIdx.x;
    const int t = threadIdx.x;
    if (t == 0) cnt = 0;
    __syncthreads();
    #pragma unroll
    for (int l = 0; l < 12; ++l) {
        int j = t + l * 256;
        if (adj[(size_t)i * N_V + j] > 0.f) {
            int p = atomicAdd(&cnt, 1);
            list[p] = j;
        }
    }
    __syncthreads();
    const int wave = t >> 6, lane = t & 63;
    float ei[8];
    #pragma unroll
    for (int k = 0; k < 8; ++k) ei[k] = emb[(size_t)i * D_E + lane + k * 64];
    float sum = 0.f;
    for (int e = wave; e < cnt; e += 4) {
        int j = list[e];
        float dot = 0.f;
        #pragma unroll
        for (int k = 0; k < 8; ++k)
            dot = fmaf(ei[k], emb[(size_t)j * D_E + lane + k * 64], dot);
        #pragma unroll
        for (int off = 32; off; off >>= 1) dot += __shfl_down(dot, off);
        if (lane == 0) {
            float d2 = sq[i] + sq[j] - 2.f * dot;
            sum += sqrtf(fmaxf(d2, 1e-12f));
        }
    }
    if (lane == 0) wsum[wave] = sum;
    __syncthreads();
    if (t == 0) {
        float tot = wsum[0] + wsum[1] + wsum[2] + wsum[3];
        atomicAdd(accum, -tot);
    }
}

__global__ void finalize(const float* __restrict__ accum, float* __restrict__ out)
{
    float loss = accum[0];
    out[0] = fmaxf(loss + 400.f, 0.f);       // triplet
    out[1] = loss;                            // embedding_loss
    out[2] = accum[1] / (float)N_V - logf(1e-8f);  // log_conf
}

// ---------------------------------------------------------------------------
extern "C" void kernel_launch(void* const* d_in, const int* in_sizes, int n_in,
                              void* d_out, int out_size, void* d_ws, size_t ws_size,
                              hipStream_t stream) {
    const float* emb_in   = (const float*)d_in[0];
    const float* adj      = (const float*)d_in[1];
    const float* W_n      = (const float*)d_in[2];
    const float* a_src_n  = (const float*)d_in[3];
    const float* a_dst_n  = (const float*)d_in[4];
    const float* W_nn     = (const float*)d_in[5];
    const float* a_src_nn = (const float*)d_in[6];
    const float* a_dst_nn = (const float*)d_in[7];
    const float* W_u      = (const float*)d_in[8];
    const float* b_u      = (const float*)d_in[9];
    const float* W_g      = (const float*)d_in[10];
    const float* a_src_g  = (const float*)d_in[11];
    const float* a_dst_g  = (const float*)d_in[12];
    float* out = (float*)d_out;

    float* ws    = (float*)d_ws;
    float* Wh_a  = ws;                                   // N*D
    float* Wh_b  = Wh_a + (size_t)N_V * D_E;             // N*D
    float* cat   = Wh_b + (size_t)N_V * D_E;             // N*2D
    float* emb0  = cat  + (size_t)N_V * 2 * D_E;         // N*D
    float* emb1  = emb0 + (size_t)N_V * D_E;             // N*D
    float* att   = emb1 + (size_t)N_V * D_E;             // N*N
    float* sq    = att  + (size_t)N_V * N_V;             // N
    float* svec  = sq   + N_V;                           // N
    float* dvec  = svec + N_V;                           // N
    float* accum = dvec + N_V;                           // 2 scalars

    hipMemcpyAsync(emb0, emb_in, (size_t)N_V * D_E * sizeof(float),
                   hipMemcpyDeviceToDevice, stream);
    hipMemsetAsync(accum, 0, 2 * sizeof(float), stream);

    dim3 blk(256);
    dim3 gW(D_E / 64, N_V / 64);   // GEMMs with N=512 output columns

    float* cur = emb0;
    float* nxt = emb1;
    for (int it = 0; it < 10; ++it) {
        // neighbor branch
        gemm_f32<0><<<gW, blk, 0, stream>>>(cur, D_E, W_n, D_E, Wh_a, D_E,
                                            N_V, D_E, D_E, nullptr, 0, nullptr);
        rowdot2<<<N_V / 4, blk, 0, stream>>>(Wh_a, a_src_n, a_dst_n, svec, dvec);
        att_softmax<0><<<N_V, blk, 0, stream>>>(adj, svec, dvec, att);
        gemm_f32<1><<<gW, blk, 0, stream>>>(att, N_V, Wh_a, D_E, cat, 2 * D_E,
                                            N_V, D_E, N_V, nullptr, 0, nullptr);
        // non-neighbor branch
        gemm_f32<0><<<gW, blk, 0, stream>>>(cur, D_E, W_nn, D_E, Wh_b, D_E,
                                            N_V, D_E, D_E, nullptr, 0, nullptr);
        rowdot2<<<N_V / 4, blk, 0, stream>>>(Wh_b, a_src_nn, a_dst_nn, svec, dvec);
        att_softmax<1><<<N_V, blk, 0, stream>>>(adj, svec, dvec, att);
        gemm_f32<1><<<gW, blk, 0, stream>>>(att, N_V, Wh_b, D_E, cat + D_E, 2 * D_E,
                                            N_V, D_E, N_V, nullptr, 0, nullptr);
        // update: emb_next = relu(emb + cat @ W_u + b_u)
        gemm_f32<2><<<gW, blk, 0, stream>>>(cat, 2 * D_E, W_u, D_E, nxt, D_E,
                                            N_V, D_E, 2 * D_E, cur, D_E, b_u);
        float* tmp = cur; cur = nxt; nxt = tmp;
    }

    // final losses
    rowsumsq<<<N_V / 4, blk, 0, stream>>>(cur, sq);
    edge_loss<<<N_V, blk, 0, stream>>>(adj, cur, sq, accum);

    gemm_f32<0><<<gW, blk, 0, stream>>>(cur, D_E, W_g, D_E, Wh_a, D_E,
                                        N_V, D_E, D_E, nullptr, 0, nullptr);
    rowdot2<<<N_V / 4, blk, 0, stream>>>(Wh_a, a_src_g, a_dst_g, svec, dvec);
    conf_kernel<<<N_V, blk, 0, stream>>>(adj, svec, dvec, accum + 1);

    finalize<<<1, 1, 0, stream>>>(accum, out);
}

// Round 2
// 2602.513 us; speedup vs baseline: 3.6552x; 3.6552x over previous
//
#include <hip/hip_runtime.h>
#include <math.h>

#define N_V 3072
#define D_E 512
constexpr float LRELU_ALPHA = 0.2f;
constexpr float NEG_INF_F = -9e15f;

typedef __attribute__((ext_vector_type(8))) short bf16x8;
typedef __attribute__((ext_vector_type(4))) float f32x4;
typedef __attribute__((ext_vector_type(4))) unsigned short ushort4v;

__device__ inline unsigned short f2bf(float f) {
    union { float f; unsigned int u; } x; x.f = f;
    unsigned int r = x.u + 0x7fffu + ((x.u >> 16) & 1u);
    return (unsigned short)(r >> 16);
}
__device__ inline float bf2f(unsigned short b) {
    union { unsigned int u; float f; } x; x.u = ((unsigned int)b) << 16;
    return x.f;
}

// ---------------------------------------------------------------------------
// bf16 MFMA GEMM: C[M,N] = A[M,K] @ B[K,N], B given TRANSPOSED (BT[N][K]).
// Tile 128x64, BK=64, 4 waves (2x2), wave tile 64x32, 16x16x32 MFMA.
// global_load_lds(16B) staging with XOR swizzle (slot ^= row&7) pre-applied
// to the global source; ds_read_b128 applies the same swizzle.
// EPI 0: store C transposed as bf16 into C0 [N][M] (ldc0 = M).
// EPI 1: ELU, store bf16 row-major into C0 (ldc0 given).
// EPI 2: relu(acc + addv + bias) -> Cf (f32, ld=N) and C0 (bf16, ldc0=N).
// ---------------------------------------------------------------------------
template<int EPI>
__global__ __launch_bounds__(256) void gemm_bf16(
    const unsigned short* __restrict__ A,   // [M][K] bf16
    const unsigned short* __restrict__ BT,  // [N][K] bf16
    int M, int N, int K,
    unsigned short* __restrict__ C0, int ldc0,
    const float* __restrict__ addv,
    const float* __restrict__ bias,
    float* __restrict__ Cf)
{
    constexpr int BM = 128, BN = 64, BK = 64;
    __shared__ unsigned short As[BM * BK];
    __shared__ unsigned short Bs[BN * BK];
    const int tid  = threadIdx.x;
    const int bm   = blockIdx.y * BM, bn = blockIdx.x * BN;
    const int lane = tid & 63, wid = tid >> 6;
    const int wr   = wid >> 1, wc = wid & 1;
    const int lr   = lane & 15, lk = lane >> 4;

    f32x4 acc[4][2];
    #pragma unroll
    for (int i = 0; i < 4; ++i)
        #pragma unroll
        for (int j = 0; j < 2; ++j)
            acc[i][j] = (f32x4)(0.f);

    auto asp = (__attribute__((address_space(3))) unsigned short*)As;
    auto bsp = (__attribute__((address_space(3))) unsigned short*)Bs;

    for (int k0 = 0; k0 < K; k0 += BK) {
        #pragma unroll
        for (int l = 0; l < 4; ++l) {           // A: 128 rows x 64 cols
            int li = l * 256 + tid;             // chunk id, 8 bf16 per chunk
            int row = li >> 3, slot = li & 7;
            int gs = slot ^ (row & 7);
            __builtin_amdgcn_global_load_lds(
                (const __attribute__((address_space(1))) void*)(A + (size_t)(bm + row) * K + k0 + gs * 8),
                (__attribute__((address_space(3))) void*)(asp + li * 8), 16, 0, 0);
        }
        #pragma unroll
        for (int l = 0; l < 2; ++l) {           // B: 64 rows x 64 cols
            int li = l * 256 + tid;
            int row = li >> 3, slot = li & 7;
            int gs = slot ^ (row & 7);
            __builtin_amdgcn_global_load_lds(
                (const __attribute__((address_space(1))) void*)(BT + (size_t)(bn + row) * K + k0 + gs * 8),
                (__attribute__((address_space(3))) void*)(bsp + li * 8), 16, 0, 0);
        }
        __syncthreads();

        #pragma unroll
        for (int ks = 0; ks < 2; ++ks) {
            bf16x8 af[4], bfr[2];
            #pragma unroll
            for (int fm = 0; fm < 4; ++fm) {
                int row = wr * 64 + fm * 16 + lr;
                int sl = (ks * 4 + lk) ^ (row & 7);
                af[fm] = *(const bf16x8*)(As + row * BK + sl * 8);
            }
            #pragma unroll
            for (int fn = 0; fn < 2; ++fn) {
                int col = wc * 32 + fn * 16 + lr;
                int sl = (ks * 4 + lk) ^ (col & 7);
                bfr[fn] = *(const bf16x8*)(Bs + col * BK + sl * 8);
            }
            #pragma unroll
            for (int fm = 0; fm < 4; ++fm)
                #pragma unroll
                for (int fn = 0; fn < 2; ++fn)
                    acc[fm][fn] = __builtin_amdgcn_mfma_f32_16x16x32_bf16(
                        af[fm], bfr[fn], acc[fm][fn], 0, 0, 0);
        }
        __syncthreads();
    }

    #pragma unroll
    for (int fm = 0; fm < 4; ++fm) {
        #pragma unroll
        for (int fn = 0; fn < 2; ++fn) {
            int row0 = bm + wr * 64 + fm * 16 + lk * 4;
            int col  = bn + wc * 32 + fn * 16 + lr;
            f32x4 v = acc[fm][fn];
            if (EPI == 0) {
                ushort4v p;
                p.x = f2bf(v[0]); p.y = f2bf(v[1]);
                p.z = f2bf(v[2]); p.w = f2bf(v[3]);
                *(ushort4v*)(C0 + (size_t)col * ldc0 + row0) = p;
            } else if (EPI == 1) {
                #pragma unroll
                for (int r = 0; r < 4; ++r) {
                    float x = v[r];
                    x = x > 0.f ? x : (expf(x) - 1.f);
                    C0[(size_t)(row0 + r) * ldc0 + col] = f2bf(x);
                }
            } else {
                #pragma unroll
                for (int r = 0; r < 4; ++r) {
                    float x = v[r] + addv[(size_t)(row0 + r) * N + col] + bias[col];
                    x = x > 0.f ? x : 0.f;
                    Cf[(size_t)(row0 + r) * N + col] = x;
                    C0[(size_t)(row0 + r) * ldc0 + col] = f2bf(x);
                }
            }
        }
    }
}

// ---------------------------------------------------------------------------
// Transpose-convert: WT[n][k] = bf16(W[k][n]).
// ---------------------------------------------------------------------------
__global__ __launch_bounds__(256) void convT_f32_bf16(
    const float* __restrict__ W, unsigned short* __restrict__ WT, int K, int Nw)
{
    int k = blockIdx.x * 256 + threadIdx.x;
    int n = blockIdx.y;
    if (k < K) WT[(size_t)n * K + k] = f2bf(W[(size_t)k * Nw + n]);
}

__global__ __launch_bounds__(256) void conv_bf16(
    const float* __restrict__ X, unsigned short* __restrict__ Y, int n)
{
    int i = blockIdx.x * 256 + threadIdx.x;
    if (i < n) Y[i] = f2bf(X[i]);
}

// ---------------------------------------------------------------------------
// s[v] = sum_f WhT[f][v]*a_src[f]; d likewise (WhT bf16 [D][N]).
// ---------------------------------------------------------------------------
__global__ __launch_bounds__(256) void rowdot2T(
    const unsigned short* __restrict__ WhT,
    const float* __restrict__ a_src, const float* __restrict__ a_dst,
    float* __restrict__ s, float* __restrict__ d)
{
    int v = blockIdx.x * 256 + threadIdx.x;
    float ss = 0.f, dd = 0.f;
    for (int f = 0; f < D_E; ++f) {
        float x = bf2f(WhT[(size_t)f * N_V + v]);
        ss = fmaf(x, a_src[f], ss);
        dd = fmaf(x, a_dst[f], dd);
    }
    s[v] = ss; d[v] = dd;
}

// sq[i] = sum(emb[i,:]^2), fp32 emb
__global__ __launch_bounds__(256) void rowsumsq(
    const float* __restrict__ emb, float* __restrict__ sq)
{
    const int wave = threadIdx.x >> 6;
    const int lane = threadIdx.x & 63;
    const int row  = blockIdx.x * 4 + wave;
    const float* w = emb + (size_t)row * D_E;
    float ss = 0.f;
    #pragma unroll
    for (int k = 0; k < 8; ++k) {
        float x = w[lane + k * 64];
        ss = fmaf(x, x, ss);
    }
    #pragma unroll
    for (int off = 32; off; off >>= 1) ss += __shfl_down(ss, off);
    if (lane == 0) sq[row] = ss;
}

// ---------------------------------------------------------------------------
// Row softmax of masked leaky_relu(s_i + d_j), writes bf16 att.
// MASKMODE 0: adj>0; MASKMODE 1: adj==0 && j!=i.
// ---------------------------------------------------------------------------
template<int MASKMODE>
__global__ __launch_bounds__(256) void att_softmax(
    const float* __restrict__ adj, const float* __restrict__ s,
    const float* __restrict__ dvec, unsigned short* __restrict__ att)
{
    const int i = blockIdx.x;
    const int t = threadIdx.x;
    const float si = s[i];
    const float4* arow = (const float4*)(adj + (size_t)i * N_V);
    const float4* dv4  = (const float4*)dvec;
    float e[3][4];
    float mloc = -3.4e38f;
    #pragma unroll
    for (int l = 0; l < 3; ++l) {
        int jv = t + l * 256;
        float4 a = arow[jv];
        float4 d = dv4[jv];
        #pragma unroll
        for (int c = 0; c < 4; ++c) {
            int j = jv * 4 + c;
            float av = ((const float*)&a)[c];
            bool keep = (MASKMODE == 0) ? (av > 0.f) : (av == 0.f && j != i);
            float x = si + ((const float*)&d)[c];
            x = x > 0.f ? x : LRELU_ALPHA * x;
            e[l][c] = keep ? x : NEG_INF_F;
            mloc = fmaxf(mloc, e[l][c]);
        }
    }
    __shared__ float red[256];
    red[t] = mloc; __syncthreads();
    for (int o = 128; o; o >>= 1) {
        if (t < o) red[t] = fmaxf(red[t], red[t + o]);
        __syncthreads();
    }
    float m = red[0]; __syncthreads();
    float zloc = 0.f;
    #pragma unroll
    for (int l = 0; l < 3; ++l)
        #pragma unroll
        for (int c = 0; c < 4; ++c) { e[l][c] = expf(e[l][c] - m); zloc += e[l][c]; }
    red[t] = zloc; __syncthreads();
    for (int o = 128; o; o >>= 1) {
        if (t < o) red[t] += red[t + o];
        __syncthreads();
    }
    const float zinv = 1.f / red[0];
    #pragma unroll
    for (int l = 0; l < 3; ++l) {
        int jv = t + l * 256;
        ushort4v p;
        p.x = f2bf(e[l][0] * zinv); p.y = f2bf(e[l][1] * zinv);
        p.z = f2bf(e[l][2] * zinv); p.w = f2bf(e[l][3] * zinv);
        *(ushort4v*)(att + (size_t)i * N_V + (size_t)jv * 4) = p;
    }
}

// ---------------------------------------------------------------------------
// Glimpse confidence: conf_i = 1/Z_i; accumulates sum_i log(conf_i + 1e-8).
// ---------------------------------------------------------------------------
__global__ __launch_bounds__(256) void conf_kernel(
    const float* __restrict__ adj, const float* __restrict__ s,
    const float* __restrict__ dvec, float* __restrict__ accum)
{
    const int i = blockIdx.x;
    const int t = threadIdx.x;
    const float si = s[i];
    const float4* arow = (const float4*)(adj + (size_t)i * N_V);
    const float4* dv4  = (const float4*)dvec;
    float e[3][4];
    float mloc = -3.4e38f;
    #pragma unroll
    for (int l = 0; l < 3; ++l) {
        int jv = t + l * 256;
        float4 a = arow[jv];
        float4 d = dv4[jv];
        #pragma unroll
        for (int c = 0; c < 4; ++c) {
            float av = ((const float*)&a)[c];
            float x = si + ((const float*)&d)[c];
            x = x > 0.f ? x : LRELU_ALPHA * x;
            e[l][c] = (av > 0.f) ? x : NEG_INF_F;
            mloc = fmaxf(mloc, e[l][c]);
        }
    }
    __shared__ float red[256];
    red[t] = mloc; __syncthreads();
    for (int o = 128; o; o >>= 1) {
        if (t < o) red[t] = fmaxf(red[t], red[t + o]);
        __syncthreads();
    }
    float m = red[0]; __syncthreads();
    float zloc = 0.f;
    #pragma unroll
    for (int l = 0; l < 3; ++l)
        #pragma unroll
        for (int c = 0; c < 4; ++c) zloc += expf(e[l][c] - m);
    red[t] = zloc; __syncthreads();
    for (int o = 128; o; o >>= 1) {
        if (t < o) red[t] += red[t + o];
        __syncthreads();
    }
    if (t == 0) {
        float conf = 1.f / red[0];
        atomicAdd(accum, logf(conf + 1e-8f));
    }
}

// ---------------------------------------------------------------------------
// Edge-only embedding loss (fp32 emb).
// ---------------------------------------------------------------------------
__global__ __launch_bounds__(256) void edge_loss(
    const float* __restrict__ adj, const float* __restrict__ emb,
    const float* __restrict__ sq, float* __restrict__ accum)
{
    __shared__ int list[1024];
    __shared__ int cnt;
    __shared__ float wsum[4];
    const int i = blockIdx.x;
    const int t = threadIdx.x;
    if (t == 0) cnt = 0;
    __syncthreads();
    #pragma unroll
    for (int l = 0; l < 12; ++l) {
        int j = t + l * 256;
        if (adj[(size_t)i * N_V + j] > 0.f) {
            int p = atomicAdd(&cnt, 1);
            list[p] = j;
        }
    }
    __syncthreads();
    const int wave = t >> 6, lane = t & 63;
    float ei[8];
    #pragma unroll
    for (int k = 0; k < 8; ++k) ei[k] = emb[(size_t)i * D_E + lane + k * 64];
    float sum = 0.f;
    for (int e = wave; e < cnt; e += 4) {
        int j = list[e];
        float dot = 0.f;
        #pragma unroll
        for (int k = 0; k < 8; ++k)
            dot = fmaf(ei[k], emb[(size_t)j * D_E + lane + k * 64], dot);
        #pragma unroll
        for (int off = 32; off; off >>= 1) dot += __shfl_down(dot, off);
        if (lane == 0) {
            float d2 = sq[i] + sq[j] - 2.f * dot;
            sum += sqrtf(fmaxf(d2, 1e-12f));
        }
    }
    if (lane == 0) wsum[wave] = sum;
    __syncthreads();
    if (t == 0) {
        float tot = wsum[0] + wsum[1] + wsum[2] + wsum[3];
        atomicAdd(accum, -tot);
    }
}

__global__ void finalize(const float* __restrict__ accum, float* __restrict__ out)
{
    float loss = accum[0];
    out[0] = fmaxf(loss + 400.f, 0.f);
    out[1] = loss;
    out[2] = accum[1] / (float)N_V - logf(1e-8f);
}

// ---------------------------------------------------------------------------
extern "C" void kernel_launch(void* const* d_in, const int* in_sizes, int n_in,
                              void* d_out, int out_size, void* d_ws, size_t ws_size,
                              hipStream_t stream) {
    const float* emb_in   = (const float*)d_in[0];
    const float* adj      = (const float*)d_in[1];
    const float* W_n      = (const float*)d_in[2];
    const float* a_src_n  = (const float*)d_in[3];
    const float* a_dst_n  = (const float*)d_in[4];
    const float* W_nn     = (const float*)d_in[5];
    const float* a_src_nn = (const float*)d_in[6];
    const float* a_dst_nn = (const float*)d_in[7];
    const float* W_u      = (const float*)d_in[8];
    const float* b_u      = (const float*)d_in[9];
    const float* W_g      = (const float*)d_in[10];
    const float* a_src_g  = (const float*)d_in[11];
    const float* a_dst_g  = (const float*)d_in[12];
    float* out = (float*)d_out;

    char* p = (char*)d_ws;
    auto alloc = [&](size_t bytes) { char* r = p; p += (bytes + 255) & ~(size_t)255; return r; };

    unsigned short* att_bf   = (unsigned short*)alloc((size_t)N_V * N_V * 2);
    unsigned short* WhT      = (unsigned short*)alloc((size_t)D_E * N_V * 2);
    unsigned short* cat_bf   = (unsigned short*)alloc((size_t)N_V * 2 * D_E * 2);
    float*          embf[2]  = { (float*)alloc((size_t)N_V * D_E * 4),
                                 (float*)alloc((size_t)N_V * D_E * 4) };
    unsigned short* embb[2]  = { (unsigned short*)alloc((size_t)N_V * D_E * 2),
                                 (unsigned short*)alloc((size_t)N_V * D_E * 2) };
    unsigned short* WnT      = (unsigned short*)alloc((size_t)D_E * D_E * 2);
    unsigned short* WnnT     = (unsigned short*)alloc((size_t)D_E * D_E * 2);
    unsigned short* WgT      = (unsigned short*)alloc((size_t)D_E * D_E * 2);
    unsigned short* WuT      = (unsigned short*)alloc((size_t)D_E * 2 * D_E * 2);
    float*          sq       = (float*)alloc(N_V * 4);
    float*          svec     = (float*)alloc(N_V * 4);
    float*          dvec     = (float*)alloc(N_V * 4);
    float*          accum    = (float*)alloc(2 * 4);

    dim3 blk(256);

    // one-time conversions
    convT_f32_bf16<<<dim3(D_E / 256, D_E), blk, 0, stream>>>(W_n,  WnT,  D_E, D_E);
    convT_f32_bf16<<<dim3(D_E / 256, D_E), blk, 0, stream>>>(W_nn, WnnT, D_E, D_E);
    convT_f32_bf16<<<dim3(D_E / 256, D_E), blk, 0, stream>>>(W_g,  WgT,  D_E, D_E);
    convT_f32_bf16<<<dim3(2 * D_E / 256, D_E), blk, 0, stream>>>(W_u, WuT, 2 * D_E, D_E);
    conv_bf16<<<(N_V * D_E) / 256, blk, 0, stream>>>(emb_in, embb[0], N_V * D_E);
    hipMemcpyAsync(embf[0], emb_in, (size_t)N_V * D_E * 4, hipMemcpyDeviceToDevice, stream);
    hipMemsetAsync(accum, 0, 2 * sizeof(float), stream);

    dim3 gW(D_E / 64, N_V / 128);   // all GEMMs: M=3072, N=512

    int cur = 0;
    for (int it = 0; it < 10; ++it) {
        int nxt = cur ^ 1;
        // neighbor branch
        gemm_bf16<0><<<gW, blk, 0, stream>>>(embb[cur], WnT, N_V, D_E, D_E,
                                             WhT, N_V, nullptr, nullptr, nullptr);
        rowdot2T<<<N_V / 256, blk, 0, stream>>>(WhT, a_src_n, a_dst_n, svec, dvec);
        att_softmax<0><<<N_V, blk, 0, stream>>>(adj, svec, dvec, att_bf);
        gemm_bf16<1><<<gW, blk, 0, stream>>>(att_bf, WhT, N_V, D_E, N_V,
                                             cat_bf, 2 * D_E, nullptr, nullptr, nullptr);
        // non-neighbor branch
        gemm_bf16<0><<<gW, blk, 0, stream>>>(embb[cur], WnnT, N_V, D_E, D_E,
                                             WhT, N_V, nullptr, nullptr, nullptr);
        rowdot2T<<<N_V / 256, blk, 0, stream>>>(WhT, a_src_nn, a_dst_nn, svec, dvec);
        att_softmax<1><<<N_V, blk, 0, stream>>>(adj, svec, dvec, att_bf);
        gemm_bf16<1><<<gW, blk, 0, stream>>>(att_bf, WhT, N_V, D_E, N_V,
                                             cat_bf + D_E, 2 * D_E, nullptr, nullptr, nullptr);
        // update: emb_next = relu(emb + cat @ W_u + b_u)
        gemm_bf16<2><<<gW, blk, 0, stream>>>(cat_bf, WuT, N_V, D_E, 2 * D_E,
                                             embb[nxt], D_E, embf[cur], b_u, embf[nxt]);
        cur = nxt;
    }

    // losses
    rowsumsq<<<N_V / 4, blk, 0, stream>>>(embf[cur], sq);
    edge_loss<<<N_V, blk, 0, stream>>>(adj, embf[cur], sq, accum);

    gemm_bf16<0><<<gW, blk, 0, stream>>>(embb[cur], WgT, N_V, D_E, D_E,
                                         WhT, N_V, nullptr, nullptr, nullptr);
    rowdot2T<<<N_V / 256, blk, 0, stream>>>(WhT, a_src_g, a_dst_g, svec, dvec);
    conf_kernel<<<N_V, blk, 0, stream>>>(adj, svec, dvec, accum + 1);

    finalize<<<1, 1, 0, stream>>>(accum, out);
}

// Round 3
// 1149.502 us; speedup vs baseline: 8.2756x; 2.2640x over previous
//
#include <hip/hip_runtime.h>
#include <math.h>

#define N_V 3072
#define D_E 512
#define EDGE_CAP 128
constexpr float LRELU_ALPHA = 0.2f;
constexpr float NEG_INF_F = -9e15f;

typedef __attribute__((ext_vector_type(8))) short bf16x8;
typedef __attribute__((ext_vector_type(4))) float f32x4;
typedef __attribute__((ext_vector_type(4))) unsigned short ushort4v;
typedef __attribute__((ext_vector_type(2))) unsigned short ushort2v;

__device__ inline unsigned short f2bf(float f) {
    union { float f; unsigned int u; } x; x.f = f;
    unsigned int r = x.u + 0x7fffu + ((x.u >> 16) & 1u);
    return (unsigned short)(r >> 16);
}
__device__ inline float bf2f(unsigned short b) {
    union { unsigned int u; float f; } x; x.u = ((unsigned int)b) << 16;
    return x.f;
}

// ---------------------------------------------------------------------------
// bf16 MFMA GEMM: C[M,N] = A[M,K] @ B[K,N], B given TRANSPOSED (BT[N][K]).
// Tile 128x64, BK=64, 4 waves (2x2), wave tile 64x32, 16x16x32 MFMA.
// EPI 1: ELU, bf16 row-major into C0 (ldc0).
// EPI 2: relu(acc + addv + bias) -> Cf (f32, ld=N) and C0 (bf16, ldc0).
// EPI 4: split: col<512 -> row-major bf16 C0 (ldc0=512);
//               col>=512 -> transposed bf16 C1 [(col-512)][M].
// ---------------------------------------------------------------------------
template<int EPI>
__global__ __launch_bounds__(256) void gemm_bf16(
    const unsigned short* __restrict__ A,   // [M][K] bf16
    const unsigned short* __restrict__ BT,  // [N][K] bf16
    int M, int N, int K,
    unsigned short* __restrict__ C0, int ldc0,
    unsigned short* __restrict__ C1,
    const float* __restrict__ addv,
    const float* __restrict__ bias,
    float* __restrict__ Cf)
{
    constexpr int BM = 128, BN = 64, BK = 64;
    __shared__ unsigned short As[BM * BK];
    __shared__ unsigned short Bs[BN * BK];
    const int tid  = threadIdx.x;
    const int bm   = blockIdx.y * BM, bn = blockIdx.x * BN;
    const int lane = tid & 63, wid = tid >> 6;
    const int wr   = wid >> 1, wc = wid & 1;
    const int lr   = lane & 15, lk = lane >> 4;

    f32x4 acc[4][2];
    #pragma unroll
    for (int i = 0; i < 4; ++i)
        #pragma unroll
        for (int j = 0; j < 2; ++j)
            acc[i][j] = (f32x4)(0.f);

    auto asp = (__attribute__((address_space(3))) unsigned short*)As;
    auto bsp = (__attribute__((address_space(3))) unsigned short*)Bs;

    for (int k0 = 0; k0 < K; k0 += BK) {
        #pragma unroll
        for (int l = 0; l < 4; ++l) {           // A: 128 rows x 64 cols
            int li = l * 256 + tid;             // 8-bf16 chunk id
            int row = li >> 3, slot = li & 7;
            int gs = slot ^ (row & 7);
            __builtin_amdgcn_global_load_lds(
                (const __attribute__((address_space(1))) void*)(A + (size_t)(bm + row) * K + k0 + gs * 8),
                (__attribute__((address_space(3))) void*)(asp + li * 8), 16, 0, 0);
        }
        #pragma unroll
        for (int l = 0; l < 2; ++l) {           // B: 64 rows x 64 cols
            int li = l * 256 + tid;
            int row = li >> 3, slot = li & 7;
            int gs = slot ^ (row & 7);
            __builtin_amdgcn_global_load_lds(
                (const __attribute__((address_space(1))) void*)(BT + (size_t)(bn + row) * K + k0 + gs * 8),
                (__attribute__((address_space(3))) void*)(bsp + li * 8), 16, 0, 0);
        }
        __syncthreads();

        #pragma unroll
        for (int ks = 0; ks < 2; ++ks) {
            bf16x8 af[4], bfr[2];
            #pragma unroll
            for (int fm = 0; fm < 4; ++fm) {
                int row = wr * 64 + fm * 16 + lr;
                int sl = (ks * 4 + lk) ^ (row & 7);
                af[fm] = *(const bf16x8*)(As + row * BK + sl * 8);
            }
            #pragma unroll
            for (int fn = 0; fn < 2; ++fn) {
                int col = wc * 32 + fn * 16 + lr;
                int sl = (ks * 4 + lk) ^ (col & 7);
                bfr[fn] = *(const bf16x8*)(Bs + col * BK + sl * 8);
            }
            #pragma unroll
            for (int fm = 0; fm < 4; ++fm)
                #pragma unroll
                for (int fn = 0; fn < 2; ++fn)
                    acc[fm][fn] = __builtin_amdgcn_mfma_f32_16x16x32_bf16(
                        af[fm], bfr[fn], acc[fm][fn], 0, 0, 0);
        }
        __syncthreads();
    }

    #pragma unroll
    for (int fm = 0; fm < 4; ++fm) {
        #pragma unroll
        for (int fn = 0; fn < 2; ++fn) {
            int row0 = bm + wr * 64 + fm * 16 + lk * 4;
            int col  = bn + wc * 32 + fn * 16 + lr;
            f32x4 v = acc[fm][fn];
            if (EPI == 1) {
                #pragma unroll
                for (int r = 0; r < 4; ++r) {
                    float x = v[r];
                    x = x > 0.f ? x : (expf(x) - 1.f);
                    C0[(size_t)(row0 + r) * ldc0 + col] = f2bf(x);
                }
            } else if (EPI == 2) {
                #pragma unroll
                for (int r = 0; r < 4; ++r) {
                    float x = v[r] + addv[(size_t)(row0 + r) * N + col] + bias[col];
                    x = x > 0.f ? x : 0.f;
                    Cf[(size_t)(row0 + r) * N + col] = x;
                    C0[(size_t)(row0 + r) * ldc0 + col] = f2bf(x);
                }
            } else { // EPI 4
                if (col < 512) {
                    #pragma unroll
                    for (int r = 0; r < 4; ++r)
                        C0[(size_t)(row0 + r) * ldc0 + col] = f2bf(v[r]);
                } else {
                    ushort4v p;
                    p.x = f2bf(v[0]); p.y = f2bf(v[1]);
                    p.z = f2bf(v[2]); p.w = f2bf(v[3]);
                    *(ushort4v*)(C1 + (size_t)(col - 512) * M + row0) = p;
                }
            }
        }
    }
}

// ---------------------------------------------------------------------------
// WT[n][k] = bf16(W[k][n])
// ---------------------------------------------------------------------------
__global__ __launch_bounds__(256) void convT_f32_bf16(
    const float* __restrict__ W, unsigned short* __restrict__ WT, int K, int Nw)
{
    int k = blockIdx.x * 256 + threadIdx.x;
    int n = blockIdx.y;
    if (k < K) WT[(size_t)n * K + k] = f2bf(W[(size_t)k * Nw + n]);
}

__global__ __launch_bounds__(256) void conv_bf16(
    const float* __restrict__ X, unsigned short* __restrict__ Y, int n)
{
    int i = blockIdx.x * 256 + threadIdx.x;
    if (i < n) Y[i] = f2bf(X[i]);
}

// ---------------------------------------------------------------------------
// One-time: packed bitmask + deterministic per-row edge list.
// threads 0..95 each own 32 consecutive columns.
// ---------------------------------------------------------------------------
__global__ __launch_bounds__(256) void build_graph(
    const float* __restrict__ adj, int* __restrict__ edges,
    int* __restrict__ deg, unsigned int* __restrict__ bitmask)
{
    const int i = blockIdx.x, t = threadIdx.x;
    __shared__ int cnts[256];
    unsigned int word = 0;
    int c = 0;
    if (t < 96) {
        #pragma unroll
        for (int b = 0; b < 32; ++b) {
            int j = t * 32 + b;
            if (adj[(size_t)i * N_V + j] > 0.f) { word |= (1u << b); ++c; }
        }
    }
    cnts[t] = c;
    __syncthreads();
    for (int o = 1; o < 256; o <<= 1) {
        int add = (t >= o) ? cnts[t - o] : 0;
        __syncthreads();
        cnts[t] += add;
        __syncthreads();
    }
    int base = cnts[t] - c;
    if (t < 96) {
        int k = 0;
        #pragma unroll
        for (int b = 0; b < 32; ++b) {
            if ((word >> b) & 1u) {
                int pos = base + k;
                if (pos < EDGE_CAP) edges[(size_t)i * EDGE_CAP + pos] = t * 32 + b;
                ++k;
            }
        }
        bitmask[(size_t)i * 96 + t] = word;
    }
    if (t == 0) deg[i] = cnts[255] < EDGE_CAP ? cnts[255] : EDGE_CAP;
}

// ---------------------------------------------------------------------------
// One-time: wv[0..5] = {W_n@as_n, W_n@ad_n, W_nn@as_nn, W_nn@ad_nn, W_g@as_g, W_g@ad_g}
// ---------------------------------------------------------------------------
__global__ __launch_bounds__(256) void matvec6(
    const float* __restrict__ W_n, const float* __restrict__ W_nn,
    const float* __restrict__ W_g,
    const float* __restrict__ as_n, const float* __restrict__ ad_n,
    const float* __restrict__ as_nn, const float* __restrict__ ad_nn,
    const float* __restrict__ as_g, const float* __restrict__ ad_g,
    float* __restrict__ wv)
{
    const int wave = threadIdx.x >> 6, lane = threadIdx.x & 63;
    const int r = blockIdx.x * 4 + wave;
    float a0 = 0, a1 = 0, a2 = 0, a3 = 0, a4 = 0, a5 = 0;
    #pragma unroll
    for (int k = 0; k < 8; ++k) {
        int c = lane + k * 64;
        float wn = W_n[(size_t)r * D_E + c];
        float wm = W_nn[(size_t)r * D_E + c];
        float wg = W_g[(size_t)r * D_E + c];
        a0 = fmaf(wn, as_n[c], a0);  a1 = fmaf(wn, ad_n[c], a1);
        a2 = fmaf(wm, as_nn[c], a2); a3 = fmaf(wm, ad_nn[c], a3);
        a4 = fmaf(wg, as_g[c], a4);  a5 = fmaf(wg, ad_g[c], a5);
    }
    #pragma unroll
    for (int off = 32; off; off >>= 1) {
        a0 += __shfl_down(a0, off); a1 += __shfl_down(a1, off);
        a2 += __shfl_down(a2, off); a3 += __shfl_down(a3, off);
        a4 += __shfl_down(a4, off); a5 += __shfl_down(a5, off);
    }
    if (lane == 0) {
        wv[0 * D_E + r] = a0; wv[1 * D_E + r] = a1;
        wv[2 * D_E + r] = a2; wv[3 * D_E + r] = a3;
        wv[4 * D_E + r] = a4; wv[5 * D_E + r] = a5;
    }
}

// ---------------------------------------------------------------------------
// outs[v][i] = emb_bf16[i,:] . wv[v]  (NV vectors). One wave per row.
// ---------------------------------------------------------------------------
template<int NV>
__global__ __launch_bounds__(256) void sd_dots(
    const unsigned short* __restrict__ emb, const float* __restrict__ wv,
    float* __restrict__ outs)
{
    const int wave = threadIdx.x >> 6, lane = threadIdx.x & 63;
    const int i = blockIdx.x * 4 + wave;
    float acc[NV];
    #pragma unroll
    for (int v = 0; v < NV; ++v) acc[v] = 0.f;
    #pragma unroll
    for (int k = 0; k < 8; ++k) {
        int c = lane + k * 64;
        float x = bf2f(emb[(size_t)i * D_E + c]);
        #pragma unroll
        for (int v = 0; v < NV; ++v) acc[v] = fmaf(x, wv[v * D_E + c], acc[v]);
    }
    #pragma unroll
    for (int off = 32; off; off >>= 1)
        #pragma unroll
        for (int v = 0; v < NV; ++v) acc[v] += __shfl_down(acc[v], off);
    if (lane == 0)
        #pragma unroll
        for (int v = 0; v < NV; ++v) outs[v * N_V + i] = acc[v];
}

// ---------------------------------------------------------------------------
// Non-neighbor softmax via bitmask: keep = !bit && j!=i. Writes bf16 att row.
// ---------------------------------------------------------------------------
__global__ __launch_bounds__(256) void softmax_nn(
    const unsigned int* __restrict__ bitmask, const float* __restrict__ s,
    const float* __restrict__ dvec, unsigned short* __restrict__ att)
{
    const int i = blockIdx.x, t = threadIdx.x;
    __shared__ unsigned int mrow[96];
    __shared__ float red[256];
    if (t < 96) mrow[t] = bitmask[(size_t)i * 96 + t];
    __syncthreads();
    const float si = s[i];
    const float4* dv4 = (const float4*)dvec;
    float e[3][4];
    float mloc = -3.4e38f;
    #pragma unroll
    for (int l = 0; l < 3; ++l) {
        int jv = t + l * 256;
        float4 d = dv4[jv];
        int j0 = jv * 4;
        unsigned int w = mrow[j0 >> 5];
        #pragma unroll
        for (int c = 0; c < 4; ++c) {
            int j = j0 + c;
            bool keep = (((w >> (j & 31)) & 1u) == 0u) && (j != i);
            float x = si + ((const float*)&d)[c];
            x = x > 0.f ? x : LRELU_ALPHA * x;
            e[l][c] = keep ? x : NEG_INF_F;
            mloc = fmaxf(mloc, e[l][c]);
        }
    }
    red[t] = mloc; __syncthreads();
    for (int o = 128; o; o >>= 1) {
        if (t < o) red[t] = fmaxf(red[t], red[t + o]);
        __syncthreads();
    }
    float m = red[0]; __syncthreads();
    float zloc = 0.f;
    #pragma unroll
    for (int l = 0; l < 3; ++l)
        #pragma unroll
        for (int c = 0; c < 4; ++c) { e[l][c] = expf(e[l][c] - m); zloc += e[l][c]; }
    red[t] = zloc; __syncthreads();
    for (int o = 128; o; o >>= 1) {
        if (t < o) red[t] += red[t + o];
        __syncthreads();
    }
    const float zinv = 1.f / red[0];
    #pragma unroll
    for (int l = 0; l < 3; ++l) {
        int jv = t + l * 256;
        ushort4v p;
        p.x = f2bf(e[l][0] * zinv); p.y = f2bf(e[l][1] * zinv);
        p.z = f2bf(e[l][2] * zinv); p.w = f2bf(e[l][3] * zinv);
        *(ushort4v*)(att + (size_t)i * N_V + (size_t)jv * 4) = p;
    }
}

// ---------------------------------------------------------------------------
// Fused sparse neighbor branch: softmax over edges + weighted sum of Wh_n rows
// + ELU, writes cat[:, 0:512] (bf16). One block per row, thread owns 2 dims.
// ---------------------------------------------------------------------------
__global__ __launch_bounds__(256) void neigh_gather(
    const int* __restrict__ edges, const int* __restrict__ deg,
    const float* __restrict__ s, const float* __restrict__ dvec,
    const unsigned short* __restrict__ Whn, unsigned short* __restrict__ cat)
{
    const int i = blockIdx.x, t = threadIdx.x;
    const int cnt = deg[i];
    __shared__ float p[EDGE_CAP];
    __shared__ int lst[EDGE_CAP];
    __shared__ float red[256];
    float ev = -3.4e38f;
    if (t < cnt) {
        int j = edges[(size_t)i * EDGE_CAP + t];
        lst[t] = j;
        float x = s[i] + dvec[j];
        x = x > 0.f ? x : LRELU_ALPHA * x;
        p[t] = x;
        ev = x;
    }
    red[t] = ev; __syncthreads();
    for (int o = 128; o; o >>= 1) {
        if (t < o) red[t] = fmaxf(red[t], red[t + o]);
        __syncthreads();
    }
    float m = red[0]; __syncthreads();
    float pe = 0.f;
    if (t < cnt) { pe = expf(p[t] - m); p[t] = pe; }
    red[t] = pe; __syncthreads();
    for (int o = 128; o; o >>= 1) {
        if (t < o) red[t] += red[t + o];
        __syncthreads();
    }
    const float zinv = 1.f / red[0];
    float a0 = 0.f, a1 = 0.f;
    for (int e = 0; e < cnt; ++e) {
        int j = lst[e];
        float w = p[e] * zinv;
        ushort2v h = *(const ushort2v*)(Whn + (size_t)j * D_E + t * 2);
        a0 = fmaf(w, bf2f(h.x), a0);
        a1 = fmaf(w, bf2f(h.y), a1);
    }
    a0 = a0 > 0.f ? a0 : (expf(a0) - 1.f);
    a1 = a1 > 0.f ? a1 : (expf(a1) - 1.f);
    ushort2v o2; o2.x = f2bf(a0); o2.y = f2bf(a1);
    *(ushort2v*)(cat + (size_t)i * (2 * D_E) + t * 2) = o2;
}

// sq[i] = sum(emb[i,:]^2), fp32
__global__ __launch_bounds__(256) void rowsumsq(
    const float* __restrict__ emb, float* __restrict__ sq)
{
    const int wave = threadIdx.x >> 6, lane = threadIdx.x & 63;
    const int row = blockIdx.x * 4 + wave;
    const float* w = emb + (size_t)row * D_E;
    float ss = 0.f;
    #pragma unroll
    for (int k = 0; k < 8; ++k) {
        float x = w[lane + k * 64];
        ss = fmaf(x, x, ss);
    }
    #pragma unroll
    for (int off = 32; off; off >>= 1) ss += __shfl_down(ss, off);
    if (lane == 0) sq[row] = ss;
}

// ---------------------------------------------------------------------------
// Edge-list embedding loss (fp32). One block per row, wave per edge-slot.
// ---------------------------------------------------------------------------
__global__ __launch_bounds__(256) void edge_loss2(
    const int* __restrict__ edges, const int* __restrict__ deg,
    const float* __restrict__ emb, const float* __restrict__ sq,
    float* __restrict__ accum)
{
    __shared__ float wsum[4];
    const int i = blockIdx.x, t = threadIdx.x;
    const int wave = t >> 6, lane = t & 63;
    const int cnt = deg[i];
    float ei[8];
    #pragma unroll
    for (int k = 0; k < 8; ++k) ei[k] = emb[(size_t)i * D_E + lane + k * 64];
    float sum = 0.f;
    for (int e = wave; e < cnt; e += 4) {
        int j = edges[(size_t)i * EDGE_CAP + e];
        float dot = 0.f;
        #pragma unroll
        for (int k = 0; k < 8; ++k)
            dot = fmaf(ei[k], emb[(size_t)j * D_E + lane + k * 64], dot);
        #pragma unroll
        for (int off = 32; off; off >>= 1) dot += __shfl_down(dot, off);
        if (lane == 0) {
            float d2 = sq[i] + sq[j] - 2.f * dot;
            sum += sqrtf(fmaxf(d2, 1e-12f));
        }
    }
    if (lane == 0) wsum[wave] = sum;
    __syncthreads();
    if (t == 0) atomicAdd(accum, -(wsum[0] + wsum[1] + wsum[2] + wsum[3]));
}

// ---------------------------------------------------------------------------
// Glimpse confidence via bitmask (keep = bit): conf_i = 1/Z_i.
// ---------------------------------------------------------------------------
__global__ __launch_bounds__(256) void conf_kernel(
    const unsigned int* __restrict__ bitmask, const float* __restrict__ s,
    const float* __restrict__ dvec, float* __restrict__ accum)
{
    const int i = blockIdx.x, t = threadIdx.x;
    __shared__ unsigned int mrow[96];
    __shared__ float red[256];
    if (t < 96) mrow[t] = bitmask[(size_t)i * 96 + t];
    __syncthreads();
    const float si = s[i];
    const float4* dv4 = (const float4*)dvec;
    float e[3][4];
    float mloc = -3.4e38f;
    #pragma unroll
    for (int l = 0; l < 3; ++l) {
        int jv = t + l * 256;
        float4 d = dv4[jv];
        int j0 = jv * 4;
        unsigned int w = mrow[j0 >> 5];
        #pragma unroll
        for (int c = 0; c < 4; ++c) {
            int j = j0 + c;
            bool keep = ((w >> (j & 31)) & 1u) != 0u;
            float x = si + ((const float*)&d)[c];
            x = x > 0.f ? x : LRELU_ALPHA * x;
            e[l][c] = keep ? x : NEG_INF_F;
            mloc = fmaxf(mloc, e[l][c]);
        }
    }
    red[t] = mloc; __syncthreads();
    for (int o = 128; o; o >>= 1) {
        if (t < o) red[t] = fmaxf(red[t], red[t + o]);
        __syncthreads();
    }
    float m = red[0]; __syncthreads();
    float zloc = 0.f;
    #pragma unroll
    for (int l = 0; l < 3; ++l)
        #pragma unroll
        for (int c = 0; c < 4; ++c) zloc += expf(e[l][c] - m);
    red[t] = zloc; __syncthreads();
    for (int o = 128; o; o >>= 1) {
        if (t < o) red[t] += red[t + o];
        __syncthreads();
    }
    if (t == 0) atomicAdd(accum, logf(1.f / red[0] + 1e-8f));
}

__global__ void finalize(const float* __restrict__ accum, float* __restrict__ out)
{
    float loss = accum[0];
    out[0] = fmaxf(loss + 400.f, 0.f);
    out[1] = loss;
    out[2] = accum[1] / (float)N_V - logf(1e-8f);
}

// ---------------------------------------------------------------------------
extern "C" void kernel_launch(void* const* d_in, const int* in_sizes, int n_in,
                              void* d_out, int out_size, void* d_ws, size_t ws_size,
                              hipStream_t stream) {
    const float* emb_in   = (const float*)d_in[0];
    const float* adj      = (const float*)d_in[1];
    const float* W_n      = (const float*)d_in[2];
    const float* a_src_n  = (const float*)d_in[3];
    const float* a_dst_n  = (const float*)d_in[4];
    const float* W_nn     = (const float*)d_in[5];
    const float* a_src_nn = (const float*)d_in[6];
    const float* a_dst_nn = (const float*)d_in[7];
    const float* W_u      = (const float*)d_in[8];
    const float* b_u      = (const float*)d_in[9];
    const float* W_g      = (const float*)d_in[10];
    const float* a_src_g  = (const float*)d_in[11];
    const float* a_dst_g  = (const float*)d_in[12];
    float* out = (float*)d_out;

    char* p = (char*)d_ws;
    auto alloc = [&](size_t bytes) { char* r = p; p += (bytes + 255) & ~(size_t)255; return r; };

    unsigned short* att_nn  = (unsigned short*)alloc((size_t)N_V * N_V * 2);
    unsigned short* Whn     = (unsigned short*)alloc((size_t)N_V * D_E * 2);
    unsigned short* WhTnn   = (unsigned short*)alloc((size_t)D_E * N_V * 2);
    unsigned short* cat_bf  = (unsigned short*)alloc((size_t)N_V * 2 * D_E * 2);
    float*          embf[2] = { (float*)alloc((size_t)N_V * D_E * 4),
                                (float*)alloc((size_t)N_V * D_E * 4) };
    unsigned short* embb[2] = { (unsigned short*)alloc((size_t)N_V * D_E * 2),
                                (unsigned short*)alloc((size_t)N_V * D_E * 2) };
    unsigned short* W2T     = (unsigned short*)alloc((size_t)(2 * D_E) * D_E * 2);
    unsigned short* WuT     = (unsigned short*)alloc((size_t)D_E * (2 * D_E) * 2);
    float*          wv      = (float*)alloc(6 * D_E * 4);
    float*          sd      = (float*)alloc(4 * N_V * 4);   // s_n,d_n,s_nn,d_nn
    float*          sdg     = (float*)alloc(2 * N_V * 4);   // s_g,d_g
    float*          sq      = (float*)alloc(N_V * 4);
    int*            edges   = (int*)alloc((size_t)N_V * EDGE_CAP * 4);
    int*            deg     = (int*)alloc(N_V * 4);
    unsigned int*   bitmask = (unsigned int*)alloc((size_t)N_V * 96 * 4);
    float*          accum   = (float*)alloc(2 * 4);

    dim3 blk(256);

    // one-time prepass
    convT_f32_bf16<<<dim3(2, D_E), blk, 0, stream>>>(W_n, W2T, D_E, D_E);
    convT_f32_bf16<<<dim3(2, D_E), blk, 0, stream>>>(W_nn, W2T + (size_t)D_E * D_E, D_E, D_E);
    convT_f32_bf16<<<dim3(4, D_E), blk, 0, stream>>>(W_u, WuT, 2 * D_E, D_E);
    conv_bf16<<<(N_V * D_E) / 256, blk, 0, stream>>>(emb_in, embb[0], N_V * D_E);
    hipMemcpyAsync(embf[0], emb_in, (size_t)N_V * D_E * 4, hipMemcpyDeviceToDevice, stream);
    hipMemsetAsync(accum, 0, 2 * sizeof(float), stream);
    build_graph<<<N_V, blk, 0, stream>>>(adj, edges, deg, bitmask);
    matvec6<<<D_E / 4, blk, 0, stream>>>(W_n, W_nn, W_g, a_src_n, a_dst_n,
                                         a_src_nn, a_dst_nn, a_src_g, a_dst_g, wv);

    dim3 gW2(16, N_V / 128);   // fused Wh GEMM: N=1024
    dim3 gG(8, N_V / 128);     // N=512 GEMMs

    int cur = 0;
    for (int it = 0; it < 10; ++it) {
        int nxt = cur ^ 1;
        sd_dots<4><<<N_V / 4, blk, 0, stream>>>(embb[cur], wv, sd);
        gemm_bf16<4><<<gW2, blk, 0, stream>>>(embb[cur], W2T, N_V, 2 * D_E, D_E,
                                              Whn, D_E, WhTnn, nullptr, nullptr, nullptr);
        softmax_nn<<<N_V, blk, 0, stream>>>(bitmask, sd + 2 * N_V, sd + 3 * N_V, att_nn);
        neigh_gather<<<N_V, blk, 0, stream>>>(edges, deg, sd, sd + N_V, Whn, cat_bf);
        gemm_bf16<1><<<gG, blk, 0, stream>>>(att_nn, WhTnn, N_V, D_E, N_V,
                                             cat_bf + D_E, 2 * D_E, nullptr, nullptr, nullptr, nullptr);
        gemm_bf16<2><<<gG, blk, 0, stream>>>(cat_bf, WuT, N_V, D_E, 2 * D_E,
                                             embb[nxt], D_E, nullptr, embf[cur], b_u, embf[nxt]);
        cur = nxt;
    }

    // losses
    rowsumsq<<<N_V / 4, blk, 0, stream>>>(embf[cur], sq);
    edge_loss2<<<N_V, blk, 0, stream>>>(edges, deg, embf[cur], sq, accum);
    sd_dots<2><<<N_V / 4, blk, 0, stream>>>(embb[cur], wv + 4 * D_E, sdg);
    conf_kernel<<<N_V, blk, 0, stream>>>(bitmask, sdg, sdg + N_V, accum + 1);

    finalize<<<1, 1, 0, stream>>>(accum, out);
}

// Round 5
// 942.892 us; speedup vs baseline: 10.0889x; 1.2191x over previous
//
#include <hip/hip_runtime.h>
#include <math.h>

#define N_V 3072
#define D_E 512
#define EDGE_CAP 128
constexpr float LRELU_ALPHA = 0.2f;
constexpr float NEG_INF_F = -9e15f;

typedef __attribute__((ext_vector_type(8))) short bf16x8;
typedef __attribute__((ext_vector_type(4))) float f32x4;
typedef __attribute__((ext_vector_type(4))) unsigned short ushort4v;
typedef __attribute__((ext_vector_type(2))) unsigned short ushort2v;

__device__ inline unsigned short f2bf(float f) {
    union { float f; unsigned int u; } x; x.f = f;
    unsigned int r = x.u + 0x7fffu + ((x.u >> 16) & 1u);
    return (unsigned short)(r >> 16);
}
__device__ inline float bf2f(unsigned short b) {
    union { unsigned int u; float f; } x; x.u = ((unsigned int)b) << 16;
    return x.f;
}

// XCD-aware bijective swizzle of the (bx,by) plane; nwg %8==0 for all grids
// here (192/384/768).
__device__ inline void xcd_swizzle(int& bx, int& by) {
    int gx = gridDim.x, nwg = gx * gridDim.y;
    int flat = by * gx + bx;
    int q = nwg >> 3;
    int swz = (flat & 7) * q + (flat >> 3);
    bx = swz % gx; by = swz / gx;
}

// ---------------------------------------------------------------------------
// bf16 MFMA GEMM: C[M,N] = A[M,K] @ B[K,N], B given TRANSPOSED (BT[N][K]).
// Tile 128x64, BK=64, 4 waves (2x2), wave tile 64x32, 16x16x32 MFMA.
// EPI 2: relu(acc + addv + bias) -> Cf (f32, ld=N) and C0 (bf16, ldc0).
// EPI 4: split: col<512 -> row-major bf16 C0 (ldc0=512);
//               col>=512 -> transposed bf16 C1 [(col-512)][M].
// ---------------------------------------------------------------------------
template<int EPI>
__global__ __launch_bounds__(256) void gemm_bf16(
    const unsigned short* __restrict__ A,   // [M][K] bf16
    const unsigned short* __restrict__ BT,  // [N][K] bf16
    int M, int N, int K,
    unsigned short* __restrict__ C0, int ldc0,
    unsigned short* __restrict__ C1,
    const float* __restrict__ addv,
    const float* __restrict__ bias,
    float* __restrict__ Cf)
{
    constexpr int BM = 128, BN = 64, BK = 64;
    __shared__ unsigned short As[BM * BK];
    __shared__ unsigned short Bs[BN * BK];
    const int tid  = threadIdx.x;
    int bxi = blockIdx.x, byi = blockIdx.y;
    xcd_swizzle(bxi, byi);
    const int bm   = byi * BM, bn = bxi * BN;
    const int lane = tid & 63, wid = tid >> 6;
    const int wr   = wid >> 1, wc = wid & 1;
    const int lr   = lane & 15, lk = lane >> 4;

    f32x4 acc[4][2];
    #pragma unroll
    for (int i = 0; i < 4; ++i)
        #pragma unroll
        for (int j = 0; j < 2; ++j)
            acc[i][j] = (f32x4)(0.f);

    auto asp = (__attribute__((address_space(3))) unsigned short*)As;
    auto bsp = (__attribute__((address_space(3))) unsigned short*)Bs;

    for (int k0 = 0; k0 < K; k0 += BK) {
        #pragma unroll
        for (int l = 0; l < 4; ++l) {
            int li = l * 256 + tid;
            int row = li >> 3, slot = li & 7;
            int gs = slot ^ (row & 7);
            __builtin_amdgcn_global_load_lds(
                (const __attribute__((address_space(1))) void*)(A + (size_t)(bm + row) * K + k0 + gs * 8),
                (__attribute__((address_space(3))) void*)(asp + li * 8), 16, 0, 0);
        }
        #pragma unroll
        for (int l = 0; l < 2; ++l) {
            int li = l * 256 + tid;
            int row = li >> 3, slot = li & 7;
            int gs = slot ^ (row & 7);
            __builtin_amdgcn_global_load_lds(
                (const __attribute__((address_space(1))) void*)(BT + (size_t)(bn + row) * K + k0 + gs * 8),
                (__attribute__((address_space(3))) void*)(bsp + li * 8), 16, 0, 0);
        }
        __syncthreads();

        #pragma unroll
        for (int ks = 0; ks < 2; ++ks) {
            bf16x8 af[4], bfr[2];
            #pragma unroll
            for (int fm = 0; fm < 4; ++fm) {
                int row = wr * 64 + fm * 16 + lr;
                int sl = (ks * 4 + lk) ^ (row & 7);
                af[fm] = *(const bf16x8*)(As + row * BK + sl * 8);
            }
            #pragma unroll
            for (int fn = 0; fn < 2; ++fn) {
                int col = wc * 32 + fn * 16 + lr;
                int sl = (ks * 4 + lk) ^ (col & 7);
                bfr[fn] = *(const bf16x8*)(Bs + col * BK + sl * 8);
            }
            #pragma unroll
            for (int fm = 0; fm < 4; ++fm)
                #pragma unroll
                for (int fn = 0; fn < 2; ++fn)
                    acc[fm][fn] = __builtin_amdgcn_mfma_f32_16x16x32_bf16(
                        af[fm], bfr[fn], acc[fm][fn], 0, 0, 0);
        }
        __syncthreads();
    }

    #pragma unroll
    for (int fm = 0; fm < 4; ++fm) {
        #pragma unroll
        for (int fn = 0; fn < 2; ++fn) {
            int row0 = bm + wr * 64 + fm * 16 + lk * 4;
            int col  = bn + wc * 32 + fn * 16 + lr;
            f32x4 v = acc[fm][fn];
            if (EPI == 2) {
                #pragma unroll
                for (int r = 0; r < 4; ++r) {
                    float x = v[r] + addv[(size_t)(row0 + r) * N + col] + bias[col];
                    x = x > 0.f ? x : 0.f;
                    Cf[(size_t)(row0 + r) * N + col] = x;
                    C0[(size_t)(row0 + r) * ldc0 + col] = f2bf(x);
                }
            } else { // EPI 4
                if (col < 512) {
                    #pragma unroll
                    for (int r = 0; r < 4; ++r)
                        C0[(size_t)(row0 + r) * ldc0 + col] = f2bf(v[r]);
                } else {
                    ushort4v p;
                    p.x = f2bf(v[0]); p.y = f2bf(v[1]);
                    p.z = f2bf(v[2]); p.w = f2bf(v[3]);
                    *(ushort4v*)(C1 + (size_t)(col - 512) * M + row0) = p;
                }
            }
        }
    }
}

// ---------------------------------------------------------------------------
// Split-K=2 variant: blockIdx.z selects K-half, fp32 partials to Cp[z][M][N].
// ---------------------------------------------------------------------------
__global__ __launch_bounds__(256) void gemm_bf16_sk(
    const unsigned short* __restrict__ A,
    const unsigned short* __restrict__ BT,
    int M, int N, int K,
    float* __restrict__ Cp)
{
    constexpr int BM = 128, BN = 64, BK = 64;
    __shared__ unsigned short As[BM * BK];
    __shared__ unsigned short Bs[BN * BK];
    const int tid  = threadIdx.x;
    int bxi = blockIdx.x, byi = blockIdx.y;
    xcd_swizzle(bxi, byi);
    const int bm   = byi * BM, bn = bxi * BN;
    const int kz   = blockIdx.z;
    const int kh   = K >> 1;
    const int kbeg = kz * kh, kend = kbeg + kh;
    const int lane = tid & 63, wid = tid >> 6;
    const int wr   = wid >> 1, wc = wid & 1;
    const int lr   = lane & 15, lk = lane >> 4;

    f32x4 acc[4][2];
    #pragma unroll
    for (int i = 0; i < 4; ++i)
        #pragma unroll
        for (int j = 0; j < 2; ++j)
            acc[i][j] = (f32x4)(0.f);

    auto asp = (__attribute__((address_space(3))) unsigned short*)As;
    auto bsp = (__attribute__((address_space(3))) unsigned short*)Bs;

    for (int k0 = kbeg; k0 < kend; k0 += BK) {
        #pragma unroll
        for (int l = 0; l < 4; ++l) {
            int li = l * 256 + tid;
            int row = li >> 3, slot = li & 7;
            int gs = slot ^ (row & 7);
            __builtin_amdgcn_global_load_lds(
                (const __attribute__((address_space(1))) void*)(A + (size_t)(bm + row) * K + k0 + gs * 8),
                (__attribute__((address_space(3))) void*)(asp + li * 8), 16, 0, 0);
        }
        #pragma unroll
        for (int l = 0; l < 2; ++l) {
            int li = l * 256 + tid;
            int row = li >> 3, slot = li & 7;
            int gs = slot ^ (row & 7);
            __builtin_amdgcn_global_load_lds(
                (const __attribute__((address_space(1))) void*)(BT + (size_t)(bn + row) * K + k0 + gs * 8),
                (__attribute__((address_space(3))) void*)(bsp + li * 8), 16, 0, 0);
        }
        __syncthreads();

        #pragma unroll
        for (int ks = 0; ks < 2; ++ks) {
            bf16x8 af[4], bfr[2];
            #pragma unroll
            for (int fm = 0; fm < 4; ++fm) {
                int row = wr * 64 + fm * 16 + lr;
                int sl = (ks * 4 + lk) ^ (row & 7);
                af[fm] = *(const bf16x8*)(As + row * BK + sl * 8);
            }
            #pragma unroll
            for (int fn = 0; fn < 2; ++fn) {
                int col = wc * 32 + fn * 16 + lr;
                int sl = (ks * 4 + lk) ^ (col & 7);
                bfr[fn] = *(const bf16x8*)(Bs + col * BK + sl * 8);
            }
            #pragma unroll
            for (int fm = 0; fm < 4; ++fm)
                #pragma unroll
                for (int fn = 0; fn < 2; ++fn)
                    acc[fm][fn] = __builtin_amdgcn_mfma_f32_16x16x32_bf16(
                        af[fm], bfr[fn], acc[fm][fn], 0, 0, 0);
        }
        __syncthreads();
    }

    float* Cz = Cp + (size_t)kz * M * N;
    #pragma unroll
    for (int fm = 0; fm < 4; ++fm) {
        #pragma unroll
        for (int fn = 0; fn < 2; ++fn) {
            int row0 = bm + wr * 64 + fm * 16 + lk * 4;
            int col  = bn + wc * 32 + fn * 16 + lr;
            #pragma unroll
            for (int r = 0; r < 4; ++r)
                Cz[(size_t)(row0 + r) * N + col] = acc[fm][fn][r];
        }
    }
}

// Combine split-K partials + ELU -> bf16 into cat[:,512:1024].
__global__ __launch_bounds__(256) void elu_combine(
    const float* __restrict__ p0, const float* __restrict__ p1,
    unsigned short* __restrict__ cat)
{
    int idx = blockIdx.x * 256 + threadIdx.x;      // 4-elem chunk id
    float4 a = ((const float4*)p0)[idx];
    float4 b = ((const float4*)p1)[idx];
    int r = idx >> 7;            // 128 chunks per 512-wide row
    int c = (idx & 127) * 4;
    float v[4] = { a.x + b.x, a.y + b.y, a.z + b.z, a.w + b.w };
    ushort4v o;
    #pragma unroll
    for (int q = 0; q < 4; ++q) {
        float x = v[q];
        x = x > 0.f ? x : (expf(x) - 1.f);
        ((unsigned short*)&o)[q] = f2bf(x);
    }
    *(ushort4v*)(cat + (size_t)r * (2 * D_E) + D_E + c) = o;
}

// ---------------------------------------------------------------------------
// WT[n][k] = bf16(W[k][n])
// ---------------------------------------------------------------------------
__global__ __launch_bounds__(256) void convT_f32_bf16(
    const float* __restrict__ W, unsigned short* __restrict__ WT, int K, int Nw)
{
    int k = blockIdx.x * 256 + threadIdx.x;
    int n = blockIdx.y;
    if (k < K) WT[(size_t)n * K + k] = f2bf(W[(size_t)k * Nw + n]);
}

__global__ __launch_bounds__(256) void conv_bf16(
    const float* __restrict__ X, unsigned short* __restrict__ Y, int n)
{
    int i = blockIdx.x * 256 + threadIdx.x;
    if (i < n) Y[i] = f2bf(X[i]);
}

// ---------------------------------------------------------------------------
// One-time: packed bitmask + deterministic per-row edge list.
// ---------------------------------------------------------------------------
__global__ __launch_bounds__(256) void build_graph(
    const float* __restrict__ adj, int* __restrict__ edges,
    int* __restrict__ deg, unsigned int* __restrict__ bitmask)
{
    const int i = blockIdx.x, t = threadIdx.x;
    __shared__ int cnts[256];
    unsigned int word = 0;
    int c = 0;
    if (t < 96) {
        #pragma unroll
        for (int b = 0; b < 32; ++b) {
            int j = t * 32 + b;
            if (adj[(size_t)i * N_V + j] > 0.f) { word |= (1u << b); ++c; }
        }
    }
    cnts[t] = c;
    __syncthreads();
    for (int o = 1; o < 256; o <<= 1) {
        int add = (t >= o) ? cnts[t - o] : 0;
        __syncthreads();
        cnts[t] += add;
        __syncthreads();
    }
    int base = cnts[t] - c;
    if (t < 96) {
        int k = 0;
        #pragma unroll
        for (int b = 0; b < 32; ++b) {
            if ((word >> b) & 1u) {
                int pos = base + k;
                if (pos < EDGE_CAP) edges[(size_t)i * EDGE_CAP + pos] = t * 32 + b;
                ++k;
            }
        }
        bitmask[(size_t)i * 96 + t] = word;
    }
    if (t == 0) deg[i] = cnts[255] < EDGE_CAP ? cnts[255] : EDGE_CAP;
}

// ---------------------------------------------------------------------------
// One-time: wv[0..5] = {W_n@as_n, W_n@ad_n, W_nn@as_nn, W_nn@ad_nn, W_g@as_g, W_g@ad_g}
// ---------------------------------------------------------------------------
__global__ __launch_bounds__(256) void matvec6(
    const float* __restrict__ W_n, const float* __restrict__ W_nn,
    const float* __restrict__ W_g,
    const float* __restrict__ as_n, const float* __restrict__ ad_n,
    const float* __restrict__ as_nn, const float* __restrict__ ad_nn,
    const float* __restrict__ as_g, const float* __restrict__ ad_g,
    float* __restrict__ wv)
{
    const int wave = threadIdx.x >> 6, lane = threadIdx.x & 63;
    const int r = blockIdx.x * 4 + wave;
    float a0 = 0, a1 = 0, a2 = 0, a3 = 0, a4 = 0, a5 = 0;
    #pragma unroll
    for (int k = 0; k < 8; ++k) {
        int c = lane + k * 64;
        float wn = W_n[(size_t)r * D_E + c];
        float wm = W_nn[(size_t)r * D_E + c];
        float wg = W_g[(size_t)r * D_E + c];
        a0 = fmaf(wn, as_n[c], a0);  a1 = fmaf(wn, ad_n[c], a1);
        a2 = fmaf(wm, as_nn[c], a2); a3 = fmaf(wm, ad_nn[c], a3);
        a4 = fmaf(wg, as_g[c], a4);  a5 = fmaf(wg, ad_g[c], a5);
    }
    #pragma unroll
    for (int off = 32; off; off >>= 1) {
        a0 += __shfl_down(a0, off); a1 += __shfl_down(a1, off);
        a2 += __shfl_down(a2, off); a3 += __shfl_down(a3, off);
        a4 += __shfl_down(a4, off); a5 += __shfl_down(a5, off);
    }
    if (lane == 0) {
        wv[0 * D_E + r] = a0; wv[1 * D_E + r] = a1;
        wv[2 * D_E + r] = a2; wv[3 * D_E + r] = a3;
        wv[4 * D_E + r] = a4; wv[5 * D_E + r] = a5;
    }
}

// ---------------------------------------------------------------------------
// outs[v][i] = emb_bf16[i,:] . wv[v]
// ---------------------------------------------------------------------------
template<int NV>
__global__ __launch_bounds__(256) void sd_dots(
    const unsigned short* __restrict__ emb, const float* __restrict__ wv,
    float* __restrict__ outs)
{
    const int wave = threadIdx.x >> 6, lane = threadIdx.x & 63;
    const int i = blockIdx.x * 4 + wave;
    float acc[NV];
    #pragma unroll
    for (int v = 0; v < NV; ++v) acc[v] = 0.f;
    #pragma unroll
    for (int k = 0; k < 8; ++k) {
        int c = lane + k * 64;
        float x = bf2f(emb[(size_t)i * D_E + c]);
        #pragma unroll
        for (int v = 0; v < NV; ++v) acc[v] = fmaf(x, wv[v * D_E + c], acc[v]);
    }
    #pragma unroll
    for (int off = 32; off; off >>= 1)
        #pragma unroll
        for (int v = 0; v < NV; ++v) acc[v] += __shfl_down(acc[v], off);
    if (lane == 0)
        #pragma unroll
        for (int v = 0; v < NV; ++v) outs[v * N_V + i] = acc[v];
}

// ---------------------------------------------------------------------------
// Fused: blocks [0,N_V) run non-neighbor softmax (writes att bf16);
// blocks [N_V,2N_V) run the sparse neighbor gather (writes cat[:,0:512]).
// sd layout: s_n = sd, d_n = sd+N, s_nn = sd+2N, d_nn = sd+3N.
// ---------------------------------------------------------------------------
__global__ __launch_bounds__(256) void nn_sm_gather(
    const unsigned int* __restrict__ bitmask,
    const int* __restrict__ edges, const int* __restrict__ deg,
    const float* __restrict__ sd,
    const unsigned short* __restrict__ Whn,
    unsigned short* __restrict__ att, unsigned short* __restrict__ cat)
{
    const int t = threadIdx.x;
    __shared__ float red[256];
    if (blockIdx.x < N_V) {
        const int i = blockIdx.x;
        const float* s = sd + 2 * N_V;
        const float* dvec = sd + 3 * N_V;
        __shared__ unsigned int mrow[96];
        if (t < 96) mrow[t] = bitmask[(size_t)i * 96 + t];
        __syncthreads();
        const float si = s[i];
        const float4* dv4 = (const float4*)dvec;
        float e[3][4];
        float mloc = -3.4e38f;
        #pragma unroll
        for (int l = 0; l < 3; ++l) {
            int jv = t + l * 256;
            float4 d = dv4[jv];
            int j0 = jv * 4;
            unsigned int w = mrow[j0 >> 5];
            #pragma unroll
            for (int c = 0; c < 4; ++c) {
                int j = j0 + c;
                bool keep = (((w >> (j & 31)) & 1u) == 0u) && (j != i);
                float x = si + ((const float*)&d)[c];
                x = x > 0.f ? x : LRELU_ALPHA * x;
                e[l][c] = keep ? x : NEG_INF_F;
                mloc = fmaxf(mloc, e[l][c]);
            }
        }
        red[t] = mloc; __syncthreads();
        for (int o = 128; o; o >>= 1) {
            if (t < o) red[t] = fmaxf(red[t], red[t + o]);
            __syncthreads();
        }
        float m = red[0]; __syncthreads();
        float zloc = 0.f;
        #pragma unroll
        for (int l = 0; l < 3; ++l)
            #pragma unroll
            for (int c = 0; c < 4; ++c) { e[l][c] = expf(e[l][c] - m); zloc += e[l][c]; }
        red[t] = zloc; __syncthreads();
        for (int o = 128; o; o >>= 1) {
            if (t < o) red[t] += red[t + o];
            __syncthreads();
        }
        const float zinv = 1.f / red[0];
        #pragma unroll
        for (int l = 0; l < 3; ++l) {
            int jv = t + l * 256;
            ushort4v p;
            p.x = f2bf(e[l][0] * zinv); p.y = f2bf(e[l][1] * zinv);
            p.z = f2bf(e[l][2] * zinv); p.w = f2bf(e[l][3] * zinv);
            *(ushort4v*)(att + (size_t)i * N_V + (size_t)jv * 4) = p;
        }
    } else {
        const int i = blockIdx.x - N_V;
        const float* s = sd;
        const float* dvec = sd + N_V;
        const int cnt = deg[i];
        __shared__ float p[EDGE_CAP];
        __shared__ int lst[EDGE_CAP];
        float ev = -3.4e38f;
        if (t < cnt) {
            int j = edges[(size_t)i * EDGE_CAP + t];
            lst[t] = j;
            float x = s[i] + dvec[j];
            x = x > 0.f ? x : LRELU_ALPHA * x;
            p[t] = x;
            ev = x;
        }
        red[t] = ev; __syncthreads();
        for (int o = 128; o; o >>= 1) {
            if (t < o) red[t] = fmaxf(red[t], red[t + o]);
            __syncthreads();
        }
        float m = red[0]; __syncthreads();
        float pe = 0.f;
        if (t < cnt) { pe = expf(p[t] - m); p[t] = pe; }
        red[t] = pe; __syncthreads();
        for (int o = 128; o; o >>= 1) {
            if (t < o) red[t] += red[t + o];
            __syncthreads();
        }
        const float zinv = 1.f / red[0];
        float a0 = 0.f, a1 = 0.f;
        for (int e = 0; e < cnt; ++e) {
            int j = lst[e];
            float w = p[e] * zinv;
            ushort2v h = *(const ushort2v*)(Whn + (size_t)j * D_E + t * 2);
            a0 = fmaf(w, bf2f(h.x), a0);
            a1 = fmaf(w, bf2f(h.y), a1);
        }
        a0 = a0 > 0.f ? a0 : (expf(a0) - 1.f);
        a1 = a1 > 0.f ? a1 : (expf(a1) - 1.f);
        ushort2v o2; o2.x = f2bf(a0); o2.y = f2bf(a1);
        *(ushort2v*)(cat + (size_t)i * (2 * D_E) + t * 2) = o2;
    }
}

// sq[i] = sum(emb[i,:]^2), fp32
__global__ __launch_bounds__(256) void rowsumsq(
    const float* __restrict__ emb, float* __restrict__ sq)
{
    const int wave = threadIdx.x >> 6, lane = threadIdx.x & 63;
    const int row = blockIdx.x * 4 + wave;
    const float* w = emb + (size_t)row * D_E;
    float ss = 0.f;
    #pragma unroll
    for (int k = 0; k < 8; ++k) {
        float x = w[lane + k * 64];
        ss = fmaf(x, x, ss);
    }
    #pragma unroll
    for (int off = 32; off; off >>= 1) ss += __shfl_down(ss, off);
    if (lane == 0) sq[row] = ss;
}

// ---------------------------------------------------------------------------
// Edge-list embedding loss (fp32 emb — bf16 is numerically unsafe here: the
// large common-mode component across embeddings makes sq+sq-2dot cancel).
// ---------------------------------------------------------------------------
__global__ __launch_bounds__(256) void edge_loss2(
    const int* __restrict__ edges, const int* __restrict__ deg,
    const float* __restrict__ emb, const float* __restrict__ sq,
    float* __restrict__ accum)
{
    __shared__ float wsum[4];
    const int i = blockIdx.x, t = threadIdx.x;
    const int wave = t >> 6, lane = t & 63;
    const int cnt = deg[i];
    float ei[8];
    #pragma unroll
    for (int k = 0; k < 8; ++k) ei[k] = emb[(size_t)i * D_E + lane + k * 64];
    float sum = 0.f;
    for (int e = wave; e < cnt; e += 4) {
        int j = edges[(size_t)i * EDGE_CAP + e];
        float dot = 0.f;
        #pragma unroll
        for (int k = 0; k < 8; ++k)
            dot = fmaf(ei[k], emb[(size_t)j * D_E + lane + k * 64], dot);
        #pragma unroll
        for (int off = 32; off; off >>= 1) dot += __shfl_down(dot, off);
        if (lane == 0) {
            float d2 = sq[i] + sq[j] - 2.f * dot;
            sum += sqrtf(fmaxf(d2, 1e-12f));
        }
    }
    if (lane == 0) wsum[wave] = sum;
    __syncthreads();
    if (t == 0) atomicAdd(accum, -(wsum[0] + wsum[1] + wsum[2] + wsum[3]));
}

// ---------------------------------------------------------------------------
// Glimpse confidence via bitmask (keep = bit): conf_i = 1/Z_i.
// ---------------------------------------------------------------------------
__global__ __launch_bounds__(256) void conf_kernel(
    const unsigned int* __restrict__ bitmask, const float* __restrict__ s,
    const float* __restrict__ dvec, float* __restrict__ accum)
{
    const int i = blockIdx.x, t = threadIdx.x;
    __shared__ unsigned int mrow[96];
    __shared__ float red[256];
    if (t < 96) mrow[t] = bitmask[(size_t)i * 96 + t];
    __syncthreads();
    const float si = s[i];
    const float4* dv4 = (const float4*)dvec;
    float e[3][4];
    float mloc = -3.4e38f;
    #pragma unroll
    for (int l = 0; l < 3; ++l) {
        int jv = t + l * 256;
        float4 d = dv4[jv];
        int j0 = jv * 4;
        unsigned int w = mrow[j0 >> 5];
        #pragma unroll
        for (int c = 0; c < 4; ++c) {
            int j = j0 + c;
            bool keep = ((w >> (j & 31)) & 1u) != 0u;
            float x = si + ((const float*)&d)[c];
            x = x > 0.f ? x : LRELU_ALPHA * x;
            e[l][c] = keep ? x : NEG_INF_F;
            mloc = fmaxf(mloc, e[l][c]);
        }
    }
    red[t] = mloc; __syncthreads();
    for (int o = 128; o; o >>= 1) {
        if (t < o) red[t] = fmaxf(red[t], red[t + o]);
        __syncthreads();
    }
    float m = red[0]; __syncthreads();
    float zloc = 0.f;
    #pragma unroll
    for (int l = 0; l < 3; ++l)
        #pragma unroll
        for (int c = 0; c < 4; ++c) zloc += expf(e[l][c] - m);
    red[t] = zloc; __syncthreads();
    for (int o = 128; o; o >>= 1) {
        if (t < o) red[t] += red[t + o];
        __syncthreads();
    }
    if (t == 0) atomicAdd(accum, logf(1.f / red[0] + 1e-8f));
}

__global__ void finalize(const float* __restrict__ accum, float* __restrict__ out)
{
    float loss = accum[0];
    out[0] = fmaxf(loss + 400.f, 0.f);
    out[1] = loss;
    out[2] = accum[1] / (float)N_V - logf(1e-8f);
}

// ---------------------------------------------------------------------------
extern "C" void kernel_launch(void* const* d_in, const int* in_sizes, int n_in,
                              void* d_out, int out_size, void* d_ws, size_t ws_size,
                              hipStream_t stream) {
    const float* emb_in   = (const float*)d_in[0];
    const float* adj      = (const float*)d_in[1];
    const float* W_n      = (const float*)d_in[2];
    const float* a_src_n  = (const float*)d_in[3];
    const float* a_dst_n  = (const float*)d_in[4];
    const float* W_nn     = (const float*)d_in[5];
    const float* a_src_nn = (const float*)d_in[6];
    const float* a_dst_nn = (const float*)d_in[7];
    const float* W_u      = (const float*)d_in[8];
    const float* b_u      = (const float*)d_in[9];
    const float* W_g      = (const float*)d_in[10];
    const float* a_src_g  = (const float*)d_in[11];
    const float* a_dst_g  = (const float*)d_in[12];
    float* out = (float*)d_out;

    char* p = (char*)d_ws;
    auto alloc = [&](size_t bytes) { char* r = p; p += (bytes + 255) & ~(size_t)255; return r; };

    unsigned short* att_nn  = (unsigned short*)alloc((size_t)N_V * N_V * 2);
    float*          Cp      = (float*)alloc((size_t)2 * N_V * D_E * 4);   // split-K partials
    unsigned short* Whn     = (unsigned short*)alloc((size_t)N_V * D_E * 2);
    unsigned short* WhTnn   = (unsigned short*)alloc((size_t)D_E * N_V * 2);
    unsigned short* cat_bf  = (unsigned short*)alloc((size_t)N_V * 2 * D_E * 2);
    float*          embf[2] = { (float*)alloc((size_t)N_V * D_E * 4),
                                (float*)alloc((size_t)N_V * D_E * 4) };
    unsigned short* embb[2] = { (unsigned short*)alloc((size_t)N_V * D_E * 2),
                                (unsigned short*)alloc((size_t)N_V * D_E * 2) };
    unsigned short* W2T     = (unsigned short*)alloc((size_t)(2 * D_E) * D_E * 2);
    unsigned short* WuT     = (unsigned short*)alloc((size_t)D_E * (2 * D_E) * 2);
    float*          wv      = (float*)alloc(6 * D_E * 4);
    float*          sd      = (float*)alloc(4 * N_V * 4);
    float*          sdg     = (float*)alloc(2 * N_V * 4);
    float*          sq      = (float*)alloc(N_V * 4);
    int*            edges   = (int*)alloc((size_t)N_V * EDGE_CAP * 4);
    int*            deg     = (int*)alloc(N_V * 4);
    unsigned int*   bitmask = (unsigned int*)alloc((size_t)N_V * 96 * 4);
    float*          accum   = (float*)alloc(2 * 4);

    dim3 blk(256);

    // one-time prepass
    convT_f32_bf16<<<dim3(2, D_E), blk, 0, stream>>>(W_n, W2T, D_E, D_E);
    convT_f32_bf16<<<dim3(2, D_E), blk, 0, stream>>>(W_nn, W2T + (size_t)D_E * D_E, D_E, D_E);
    convT_f32_bf16<<<dim3(4, D_E), blk, 0, stream>>>(W_u, WuT, 2 * D_E, D_E);
    conv_bf16<<<(N_V * D_E) / 256, blk, 0, stream>>>(emb_in, embb[0], N_V * D_E);
    hipMemcpyAsync(embf[0], emb_in, (size_t)N_V * D_E * 4, hipMemcpyDeviceToDevice, stream);
    hipMemsetAsync(accum, 0, 2 * sizeof(float), stream);
    build_graph<<<N_V, blk, 0, stream>>>(adj, edges, deg, bitmask);
    matvec6<<<D_E / 4, blk, 0, stream>>>(W_n, W_nn, W_g, a_src_n, a_dst_n,
                                         a_src_nn, a_dst_nn, a_src_g, a_dst_g, wv);

    dim3 gW2(16, N_V / 128);        // fused Wh GEMM: N=1024
    dim3 gG(8, N_V / 128);          // N=512 GEMMs
    dim3 gSK(8, N_V / 128, 2);      // split-K big GEMM

    int cur = 0;
    for (int it = 0; it < 10; ++it) {
        int nxt = cur ^ 1;
        sd_dots<4><<<N_V / 4, blk, 0, stream>>>(embb[cur], wv, sd);
        gemm_bf16<4><<<gW2, blk, 0, stream>>>(embb[cur], W2T, N_V, 2 * D_E, D_E,
                                              Whn, D_E, WhTnn, nullptr, nullptr, nullptr);
        nn_sm_gather<<<2 * N_V, blk, 0, stream>>>(bitmask, edges, deg, sd,
                                                  Whn, att_nn, cat_bf);
        gemm_bf16_sk<<<gSK, blk, 0, stream>>>(att_nn, WhTnn, N_V, D_E, N_V, Cp);
        elu_combine<<<(N_V * D_E) / (4 * 256), blk, 0, stream>>>(
            Cp, Cp + (size_t)N_V * D_E, cat_bf);
        gemm_bf16<2><<<gG, blk, 0, stream>>>(cat_bf, WuT, N_V, D_E, 2 * D_E,
                                             embb[nxt], D_E, nullptr, embf[cur], b_u, embf[nxt]);
        cur = nxt;
    }

    // losses
    rowsumsq<<<N_V / 4, blk, 0, stream>>>(embf[cur], sq);
    edge_loss2<<<N_V, blk, 0, stream>>>(edges, deg, embf[cur], sq, accum);
    sd_dots<2><<<N_V / 4, blk, 0, stream>>>(embb[cur], wv + 4 * D_E, sdg);
    conf_kernel<<<N_V, blk, 0, stream>>>(bitmask, sdg, sdg + N_V, accum + 1);

    finalize<<<1, 1, 0, stream>>>(accum, out);
}